// Round 7
// baseline (380.244 us; speedup 1.0000x reference)
//
#include <hip/hip_runtime.h>

// Problem constants: B=1024, T=200, D=128, H=128
#define T_SZ 200
#define H_SZ 128

typedef __attribute__((ext_vector_type(8))) short    bf16x8;
typedef __attribute__((ext_vector_type(4))) float    f32x4;
typedef __attribute__((ext_vector_type(4))) int      i32x4;
typedef __attribute__((ext_vector_type(2))) unsigned u32x2;

__device__ __forceinline__ unsigned short f2bf(float f) {  // weight init only
  unsigned u = __builtin_bit_cast(unsigned, f);
  u += 0x7fffu + ((u >> 16) & 1u);
  return (unsigned short)(u >> 16);
}
// Single-instruction packed f32->bf16 (RNE, same rounding as f2bf).
__device__ __forceinline__ unsigned cvt_pk_bf16(float a, float b) {
  unsigned r;
  asm("v_cvt_pk_bf16_f32 %0, %1, %2" : "=v"(r) : "v"(a), "v"(b));
  return r;
}
__device__ __forceinline__ float sigmoid_fast(float x) {
  float e = __builtin_amdgcn_exp2f(-1.442695041f * x);
  return __builtin_amdgcn_rcpf(1.0f + e);
}
__device__ __forceinline__ float tanh_fast(float x) {
  float e = __builtin_amdgcn_exp2f(2.885390082f * x);
  return 1.0f - 2.0f * __builtin_amdgcn_rcpf(e + 1.0f);
}
// lgkmcnt(0)-only barrier: does NOT drain vmcnt (global stores / register
// prefetch loads stay in flight). 0xc07f = vmcnt(63) expcnt(7) lgkmcnt(0).
__device__ __forceinline__ void ldsbar() {
  __asm__ __volatile__("" ::: "memory");
  __builtin_amdgcn_s_waitcnt(0xc07f);
  __builtin_amdgcn_s_barrier();
  __asm__ __volatile__("" ::: "memory");
}

#define MFMA __builtin_amdgcn_mfma_f32_16x16x32_bf16

// ---------------------------------------------------------------------------
// Fused GRU, transposed MFMA, 4 WAVES (256 thr, 1 wave/SIMD).
// Rationale: the per-CU LDS pipe was the bottleneck and every wave reads
// IDENTICAL data fragments (haf/rhf/xaf are lane-indexed only — waves differ
// only in register-resident weights). 4 waves halve the LDS read traffic at
// unchanged per-SIMD MFMA/VALU load. Wave w owns tiles {2w,2w+1} of r
// (cols 32w..+32), u (128+32w..+32), cand/h (32w..+32): 48 MFMA/wave/step.
// lane (m16,q) holds batchrow m16, cols (2w+t2)*16 + q*4 .. +4 — r,u,c,h
// element-aligned in registers; rh/h publishes are contiguous b64 writes;
// Y is dwordx4 per tile; slen one scalar/lane.
// Phase structure:
//   P1(t): haf read -> r-MFMA(4x 2-chain, C-init = x-proj) -> sigmoid -> rh.
//   P2(t): rhf/xaf read; u-MFMA (reg-only, fills shadow); cand-MFMA;
//          xproj(t+1) (24 MFMA, h-independent); activations; h publish.
// x staged coalesced through LDS (dbuf + 2-regpair global prefetch rotation).
// ---------------------------------------------------------------------------
__global__ __launch_bounds__(256, 1) void gru_fused(
    const float* __restrict__ X,    // [B,T,D]
    const int*   __restrict__ seq_len,
    const float* __restrict__ Wg,   // [256,256] rows 0..127 x-part, 128.. h-part
    const float* __restrict__ bg,   // [256]
    const float* __restrict__ Wc,   // [256,128] rows 0..127 x-part, 128.. rh-part
    const float* __restrict__ bc,   // [128]
    float* __restrict__ Y)          // [B,T,H]
{
  __shared__ unsigned short hA[16 * 136];      // h bf16, A-layout [row][k]
  __shared__ unsigned short rhA[16 * 136];     // r*h bf16, A-layout
  __shared__ unsigned short xA[2][16 * 136];   // x bf16, A-layout, dbuf

  const int tid  = threadIdx.x;
  const int lane = tid & 63;
  const int w    = tid >> 6;   // 0..3
  const int m16  = lane & 15;
  const int q    = lane >> 4;

  // ---- weight fragments (MFMA A-operands), 2 tiles per gate per wave ----
  bf16x8 wr[2][8], wu[2][8], wc[2][8];
  #pragma unroll
  for (int t2 = 0; t2 < 2; ++t2) {
    const int colr = (2 * w + t2) * 16 + m16;
    #pragma unroll
    for (int kb = 0; kb < 8; ++kb) {
      bf16x8 fr, fu, fc;
      #pragma unroll
      for (int j = 0; j < 8; ++j) {
        const int k = kb * 32 + q * 8 + j;
        fr[j] = (short)f2bf(Wg[(size_t)k * 256 + colr]);
        fu[j] = (short)f2bf(Wg[(size_t)k * 256 + 128 + colr]);
        fc[j] = (short)f2bf(Wc[(size_t)k * 128 + colr]);
      }
      wr[t2][kb] = fr; wu[t2][kb] = fu; wc[t2][kb] = fc;
    }
  }
  f32x4 br4[2], bu4[2], bcc4[2];
  #pragma unroll
  for (int t2 = 0; t2 < 2; ++t2) {
    const int c4 = (2 * w + t2) * 16 + q * 4;
    br4[t2]  = *(const f32x4*)&bg[c4];
    bu4[t2]  = *(const f32x4*)&bg[128 + c4];
    bcc4[t2] = *(const f32x4*)&bc[c4];
  }

  const int bt   = blockIdx.x;  // 0..63
  const int slen = seq_len[bt * 16 + m16];

  float h0[4] = {0.f, 0.f, 0.f, 0.f};   // tile 2w,   cols q*4+i
  float h1[4] = {0.f, 0.f, 0.f, 0.f};   // tile 2w+1

  for (int idx = tid; idx < 16 * 136; idx += 256) hA[idx] = 0;

  // ---- x staging (coalesced): thread loads 8 floats of the 16x128 tile ----
  const int xrow = tid >> 4;        // 0..15
  const int xk8  = (tid & 15) * 8;  // k offset, 8 floats
  const float* xbase = X + (size_t)(bt * 16 + xrow) * T_SZ * 128 + xk8;

  auto xload = [&](int t, f32x4& a, f32x4& b) {
    const float* p = xbase + (size_t)t * 128;
    a = *(const f32x4*)p;
    b = *(const f32x4*)(p + 4);
  };
  auto xstage = [&](int buf, const f32x4& a, const f32x4& b) {
    i32x4 pk = { (int)cvt_pk_bf16(a.x, a.y), (int)cvt_pk_bf16(a.z, a.w),
                 (int)cvt_pk_bf16(b.x, b.y), (int)cvt_pk_bf16(b.z, b.w) };
    *(i32x4*)&xA[buf][xrow * 136 + xk8] = pk;
  };

  // Prologue: x(0),x(1) staged; x(2),x(3) in prefetch reg-pairs.
  f32x4 t0a, t0b, t1a, t1b, xrEa, xrEb, xrOa, xrOb;
  xload(0, t0a, t0b); xload(1, t1a, t1b);
  xstage(0, t0a, t0b); xstage(1, t1a, t1b);
  xload(2, xrEa, xrEb); xload(3, xrOa, xrOb);
  ldsbar();  // zero-init + xA[0],xA[1] visible

  // xproj(0): r/u/cand x-parts for the first step (MFMA C-inits, bias folded).
  f32x4 axr[2], axu[2], ccp[2];
  {
    bf16x8 xaf[4];
    #pragma unroll
    for (int kb = 0; kb < 4; ++kb)
      xaf[kb] = __builtin_bit_cast(bf16x8, *(const i32x4*)&xA[0][m16 * 136 + kb * 32 + q * 8]);
    #pragma unroll
    for (int t2 = 0; t2 < 2; ++t2) {
      f32x4 c_ = bcc4[t2], r_ = br4[t2], u_ = bu4[t2];
      #pragma unroll
      for (int kb = 0; kb < 4; ++kb) {
        c_ = MFMA(wc[t2][kb], xaf[kb], c_, 0, 0, 0);
        r_ = MFMA(wr[t2][kb], xaf[kb], r_, 0, 0, 0);
        u_ = MFMA(wu[t2][kb], xaf[kb], u_, 0, 0, 0);
      }
      ccp[t2] = c_; axr[t2] = r_; axu[t2] = u_;
    }
  }
  ldsbar();  // prologue xA[0] readers drained before P1(0) overwrites it

  float* const yb0 = Y + (size_t)(bt * 16 + m16) * T_SZ * H_SZ + 2 * w * 16 + q * 4;
  const int lw0 = m16 * 136 + 2 * w * 16 + q * 4;   // halfword idx, tile0
  const int lw1 = lw0 + 16;                         // tile1

  auto step = [&](int t, f32x4& xra, f32x4& xrb) {
    // ---- P1: r gates + rh publish ONLY (minimal pre-barrier path) ----
    bf16x8 haf[4];
    #pragma unroll
    for (int kb = 0; kb < 4; ++kb)
      haf[kb] = __builtin_bit_cast(bf16x8, *(const i32x4*)&hA[m16 * 136 + kb * 32 + q * 8]);

    // stage x(t+2) into xA[t&1] (readers drained at bar2(t-1)); reload regs
    if (t < 198) xstage(t & 1, xra, xrb);
    if (t < 196) xload(t + 4, xra, xrb);

    // r: 4 independent 2-deep chains (2 tiles x 2), C-init = bias + x-proj
    f32x4 r0a = axr[0], r0b = {0.f,0.f,0.f,0.f};
    f32x4 r1a = axr[1], r1b = {0.f,0.f,0.f,0.f};
    r0a = MFMA(wr[0][4], haf[0], r0a, 0, 0, 0);
    r1a = MFMA(wr[1][4], haf[0], r1a, 0, 0, 0);
    r0a = MFMA(wr[0][5], haf[1], r0a, 0, 0, 0);
    r1a = MFMA(wr[1][5], haf[1], r1a, 0, 0, 0);
    r0b = MFMA(wr[0][6], haf[2], r0b, 0, 0, 0);
    r1b = MFMA(wr[1][6], haf[2], r1b, 0, 0, 0);
    r0b = MFMA(wr[0][7], haf[3], r0b, 0, 0, 0);
    r1b = MFMA(wr[1][7], haf[3], r1b, 0, 0, 0);

    // rh = sigmoid(r) * h — register op; publish 2 contiguous b64
    float s00 = sigmoid_fast(r0a[0] + r0b[0]) * h0[0];
    float s01 = sigmoid_fast(r0a[1] + r0b[1]) * h0[1];
    float s02 = sigmoid_fast(r0a[2] + r0b[2]) * h0[2];
    float s03 = sigmoid_fast(r0a[3] + r0b[3]) * h0[3];
    float s10 = sigmoid_fast(r1a[0] + r1b[0]) * h1[0];
    float s11 = sigmoid_fast(r1a[1] + r1b[1]) * h1[1];
    float s12 = sigmoid_fast(r1a[2] + r1b[2]) * h1[2];
    float s13 = sigmoid_fast(r1a[3] + r1b[3]) * h1[3];
    *(u32x2*)&rhA[lw0] = (u32x2){ cvt_pk_bf16(s00, s01), cvt_pk_bf16(s02, s03) };
    *(u32x2*)&rhA[lw1] = (u32x2){ cvt_pk_bf16(s10, s11), cvt_pk_bf16(s12, s13) };
    ldsbar();

    // ---- P2: u + candidate + xproj(t+1) + h update ----
    bf16x8 rhf[4];
    #pragma unroll
    for (int kb = 0; kb < 4; ++kb)
      rhf[kb] = __builtin_bit_cast(bf16x8, *(const i32x4*)&rhA[m16 * 136 + kb * 32 + q * 8]);
    bf16x8 xaf2[4];
    if (t < 199) {
      const unsigned short* xb = xA[(t + 1) & 1];
      #pragma unroll
      for (int kb = 0; kb < 4; ++kb)
        xaf2[kb] = __builtin_bit_cast(bf16x8, *(const i32x4*)&xb[m16 * 136 + kb * 32 + q * 8]);
    }

    // u: register-only inputs (haf held) — fills the rhf/xaf2 read shadow.
    f32x4 u0 = axu[0], u1 = axu[1];
    u0 = MFMA(wu[0][4], haf[0], u0, 0, 0, 0);
    u1 = MFMA(wu[1][4], haf[0], u1, 0, 0, 0);
    u0 = MFMA(wu[0][5], haf[1], u0, 0, 0, 0);
    u1 = MFMA(wu[1][5], haf[1], u1, 0, 0, 0);
    u0 = MFMA(wu[0][6], haf[2], u0, 0, 0, 0);
    u1 = MFMA(wu[1][6], haf[2], u1, 0, 0, 0);
    u0 = MFMA(wu[0][7], haf[3], u0, 0, 0, 0);
    u1 = MFMA(wu[1][7], haf[3], u1, 0, 0, 0);

    // cand: 2 tiles x (2+2) chains, C-init = bias + x-proj
    f32x4 c0a = ccp[0], c0b = {0.f,0.f,0.f,0.f};
    f32x4 c1a = ccp[1], c1b = {0.f,0.f,0.f,0.f};
    c0a = MFMA(wc[0][4], rhf[0], c0a, 0, 0, 0);
    c1a = MFMA(wc[1][4], rhf[0], c1a, 0, 0, 0);
    c0a = MFMA(wc[0][5], rhf[1], c0a, 0, 0, 0);
    c1a = MFMA(wc[1][5], rhf[1], c1a, 0, 0, 0);
    c0b = MFMA(wc[0][6], rhf[2], c0b, 0, 0, 0);
    c1b = MFMA(wc[1][6], rhf[2], c1b, 0, 0, 0);
    c0b = MFMA(wc[0][7], rhf[3], c0b, 0, 0, 0);
    c1b = MFMA(wc[1][7], rhf[3], c1b, 0, 0, 0);

    if (t < 199) {  // xproj(t+1): h-independent filler (24 MFMA)
      #pragma unroll
      for (int t2 = 0; t2 < 2; ++t2) {
        f32x4 c_ = bcc4[t2], r_ = br4[t2], u_ = bu4[t2];
        #pragma unroll
        for (int kb = 0; kb < 4; ++kb) {
          c_ = MFMA(wc[t2][kb], xaf2[kb], c_, 0, 0, 0);
          r_ = MFMA(wr[t2][kb], xaf2[kb], r_, 0, 0, 0);
          u_ = MFMA(wu[t2][kb], xaf2[kb], u_, 0, 0, 0);
        }
        ccp[t2] = c_; axr[t2] = r_; axu[t2] = u_;
      }
    }

    const bool valid = (t < slen);
    f32x4 y0, y1;
    #pragma unroll
    for (int i = 0; i < 4; ++i) {
      float uu = sigmoid_fast(u0[i]);
      float cc = tanh_fast(c0a[i] + c0b[i]);
      float hn = uu * (h0[i] - cc) + cc;   // u*h + (1-u)*c
      h0[i] = valid ? hn : h0[i];
      y0[i] = valid ? hn : 0.0f;
    }
    #pragma unroll
    for (int i = 0; i < 4; ++i) {
      float uu = sigmoid_fast(u1[i]);
      float cc = tanh_fast(c1a[i] + c1b[i]);
      float hn = uu * (h1[i] - cc) + cc;
      h1[i] = valid ? hn : h1[i];
      y1[i] = valid ? hn : 0.0f;
    }
    *(f32x4*)(yb0 + (size_t)t * H_SZ)      = y0;   // dwordx4 per tile
    *(f32x4*)(yb0 + (size_t)t * H_SZ + 16) = y1;
    *(u32x2*)&hA[lw0] = (u32x2){ cvt_pk_bf16(h0[0], h0[1]), cvt_pk_bf16(h0[2], h0[3]) };
    *(u32x2*)&hA[lw1] = (u32x2){ cvt_pk_bf16(h1[0], h1[1]), cvt_pk_bf16(h1[2], h1[3]) };
    ldsbar();
  };

  // 2-step unroll rotates the x prefetch reg-pairs (E: even t, O: odd t).
  for (int t = 0; t < 200; t += 2) {
    step(t,     xrEa, xrEb);
    step(t + 1, xrOa, xrOb);
  }
}

extern "C" void kernel_launch(void* const* d_in, const int* in_sizes, int n_in,
                              void* d_out, int out_size, void* d_ws, size_t ws_size,
                              hipStream_t stream) {
  const float* X   = (const float*)d_in[0];
  const int*   seq = (const int*)  d_in[1];
  const float* Wg  = (const float*)d_in[2];
  const float* bg  = (const float*)d_in[3];
  const float* Wc  = (const float*)d_in[4];
  const float* bc  = (const float*)d_in[5];
  float* Y = (float*)d_out;
  (void)d_ws; (void)ws_size;

  hipLaunchKernelGGL(gru_fused, dim3(64), dim3(256), 0, stream,
                     X, seq, Wg, bg, Wc, bc, Y);
}